// Round 7
// baseline (372.899 us; speedup 1.0000x reference)
//
#include <hip/hip_runtime.h>
#include <hip/hip_cooperative_groups.h>

namespace cg = cooperative_groups;

#define BB 8
#define C 64
#define HH 128
#define WW 128
#define HW (HH*WW)

#define TS 72        // LDS channel stride (ushorts) for halo tile
#define NPX 324      // 18*18 halo tile pixels

typedef __attribute__((ext_vector_type(8))) short short8;
typedef __attribute__((ext_vector_type(4))) unsigned short us4;
typedef __attribute__((ext_vector_type(4))) float f32x4;

__device__ inline unsigned short f2bf(float f) {
    union { float f; unsigned u; } v; v.f = f;
    unsigned r = v.u + 0x7fff + ((v.u >> 16) & 1);   // RNE
    return (unsigned short)(r >> 16);
}
__device__ inline float bf2f(unsigned short h) {
    union { unsigned u; float f; } v; v.u = ((unsigned)h) << 16;
    return v.f;
}

// ---------------------------------------------------------------------------
// conv 3x3 implicit-GEMM phase body (shared by mega-kernel and fallback).
// FIRST:  in = x fp32 NCHW -> out = x0 bf16 NHWC (+bias) + fused mean -> m
// !FIRST: in = y bf16 NHWC -> out = fp32 NCHW (+bias+residual x)
// ---------------------------------------------------------------------------
template<bool FIRST>
__device__ __forceinline__ void conv_phase(
    const void* __restrict__ in,
    const unsigned short* __restrict__ wb,   // [9][64][64] bf16 (B^T)
    const float* __restrict__ bias,
    const float* __restrict__ res,
    void* __restrict__ outp,
    float* __restrict__ m,
    unsigned short* tile, float* sredf,
    const int b, const int h0, const int wc0, const int t)
{
    {
        const int pxi = t & 31, g = t >> 5;          // g = channel octet
        for (int px = pxi; px < NPX; px += 32) {
            int th = px / 18, tw = px - th*18;
            int gh = h0 + th - 1, gw = wc0 + tw - 1;
            short8 v = {0,0,0,0,0,0,0,0};
            if ((unsigned)gh < HH && (unsigned)gw < WW) {
                if (FIRST) {
                    const float* sp = (const float*)in
                        + ((size_t)(b*C + g*8)*HW + gh*WW + gw);
#pragma unroll
                    for (int k = 0; k < 8; ++k) v[k] = (short)f2bf(sp[k*HW]);
                } else {
                    v = *(const short8*)((const unsigned short*)in
                        + ((size_t)(b*HW) + gh*WW + gw)*C + g*8);
                }
            }
            *(short8*)&tile[px*TS + g*8] = v;
        }
    }
    __syncthreads();

    const int wid = t >> 6, ln = t & 63;
    const int l15 = ln & 15, q = ln >> 4;

    f32x4 acc[4][4];
#pragma unroll
    for (int mg = 0; mg < 4; ++mg)
#pragma unroll
        for (int nt = 0; nt < 4; ++nt) acc[mg][nt] = (f32x4){0.f,0.f,0.f,0.f};

#pragma unroll 1
    for (int p = 0; p < 9; ++p) {
        const int dh = p / 3, dw = p - dh*3;
#pragma unroll
        for (int ks = 0; ks < 2; ++ks) {
            short8 bfrag[4];
#pragma unroll
            for (int nt = 0; nt < 4; ++nt)
                bfrag[nt] = *(const short8*)&wb[((size_t)(p*C) + nt*16 + l15)*C + ks*32 + q*8];
            short8 afrag[4];
#pragma unroll
            for (int mg = 0; mg < 4; ++mg) {
                const int r = wid*4 + mg;
                afrag[mg] = *(const short8*)&tile[((r+dh)*18 + l15 + dw)*TS + ks*32 + q*8];
            }
#pragma unroll
            for (int mg = 0; mg < 4; ++mg)
#pragma unroll
                for (int nt = 0; nt < 4; ++nt)
                    acc[mg][nt] = __builtin_amdgcn_mfma_f32_16x16x32_bf16(
                        afrag[mg], bfrag[nt], acc[mg][nt], 0, 0, 0);
        }
    }

    if (FIRST) {
        unsigned short* x0o = (unsigned short*)outp;
#pragma unroll
        for (int nt = 0; nt < 4; ++nt) {
            const int oc = nt*16 + l15;
            const float bv = bias[oc];
            float s = 0.f;
#pragma unroll
            for (int mg = 0; mg < 4; ++mg) {
                const int hh = h0 + wid*4 + mg;
#pragma unroll
                for (int reg = 0; reg < 4; ++reg) {
                    const int wwp = wc0 + q*4 + reg;
                    const unsigned short sv = f2bf(acc[mg][nt][reg] + bv);
                    x0o[((size_t)(b*HW) + hh*WW + wwp)*C + oc] = sv;
                    s += bf2f(sv);   // mean of rounded bf16 values (matches old path)
                }
            }
            s += __shfl_xor(s, 16);  // sum over q (px-col groups)
            s += __shfl_xor(s, 32);
            if (q == 0) sredf[(wid*4 + nt)*16 + l15] = s;
        }
        __syncthreads();
        if (t < 64) {
            const int nt2 = t >> 4, l2 = t & 15;
            float s = sredf[(0*4 + nt2)*16 + l2] + sredf[(1*4 + nt2)*16 + l2]
                    + sredf[(2*4 + nt2)*16 + l2] + sredf[(3*4 + nt2)*16 + l2];
            atomicAdd(&m[b*C + t], s * (1.f/(float)HW));
        }
        __syncthreads();
    } else {
        float* outg = (float*)outp;
#pragma unroll
        for (int mg = 0; mg < 4; ++mg) {
            const int hh = h0 + wid*4 + mg;
#pragma unroll
            for (int nt = 0; nt < 4; ++nt) {
                const int oc = nt*16 + l15;
                const float bv = bias[oc];
                const size_t base = (size_t)(b*C + oc)*HW + hh*WW + wc0 + q*4;
                const float4 rv = *(const float4*)&res[base];
                float4 ov;
                ov.x = acc[mg][nt][0] + bv + rv.x;
                ov.y = acc[mg][nt][1] + bv + rv.y;
                ov.z = acc[mg][nt][2] + bv + rv.z;
                ov.w = acc[mg][nt][3] + bv + rv.w;
                *(float4*)&outg[base] = ov;
            }
        }
    }
}

// ---------------------------------------------------------------------------
// Fused phase body (round-6 proven): depthwise3x3 + ECA (att[64]) -> LDS
// A-matrix (XOR-swizzled) -> SWAPPED-operand MFMA filter GEMM (reg-axis walks
// oc -> us4 vector consume) -> leaky -> swizzled ybuf -> coalesced NHWC store.
// ---------------------------------------------------------------------------
__device__ __forceinline__ void fused_phase(
    const unsigned short* __restrict__ x0,
    const float* __restrict__ w1, const float* __restrict__ b1,
    const float* __restrict__ w2, const float* __restrict__ b2,
    const unsigned short* __restrict__ wb3,
    const float* __restrict__ b3r,
    const float* __restrict__ m,
    unsigned short* __restrict__ y,
    unsigned short* tile, unsigned short* alds, float* att,
    const int b, const int h0, const int wc0, const int t)
{
    if (t < 64) {   // per-block ECA + b1 term (uniform over pixels)
        const float mc = m[b*C + t];
        const float mp = (t > 0)  ? m[b*C + t - 1] : 0.f;
        const float mn = (t < 63) ? m[b*C + t + 1] : 0.f;
        att[t] = b1[t] + fmaf(w2[0], mp, fmaf(w2[1], mc, fmaf(w2[2], mn, b2[0])));
    }
    {
        const int pxi = t & 31, g = t >> 5;
        for (int px = pxi; px < NPX; px += 32) {
            int th = px / 18, tw = px - th*18;
            int gh = h0 + th - 1, gw = wc0 + tw - 1;
            short8 v = {0,0,0,0,0,0,0,0};
            if ((unsigned)gh < HH && (unsigned)gw < WW)
                v = *(const short8*)&x0[((size_t)(b*HW) + gh*WW + gw)*C + g*8];
            *(short8*)&tile[px*TS + g*8] = v;
        }
    }
    __syncthreads();

    const int r = t >> 4, cc = t & 15;
    const unsigned short* tbase = tile + (r*18 + cc)*TS;

    // ---- phase 1: depthwise + att -> outv[64] ----
    float outv[64];
#pragma unroll
    for (int g = 0; g < 8; ++g) {
        float dw8[8];
#pragma unroll
        for (int k = 0; k < 8; ++k) dw8[k] = 0.f;
#pragma unroll
        for (int j = 0; j < 9; ++j) {
            short8 v = *(const short8*)&tbase[((j/3)*18 + (j%3))*TS + g*8];
#pragma unroll
            for (int k = 0; k < 8; ++k)
                dw8[k] = fmaf(w1[(g*8+k)*9 + j], bf2f((unsigned short)v[k]), dw8[k]);
        }
#pragma unroll
        for (int k = 0; k < 8; ++k) {
            const int c = g*8 + k;
            outv[c] = dw8[k] + att[c];
        }
    }

    // ---- write A[px][k] bf16 to LDS, XOR-swizzled 16B groups ----
    {
        const int sw = t & 7;
#pragma unroll
        for (int g = 0; g < 8; ++g) {
            short8 v;
#pragma unroll
            for (int k = 0; k < 8; ++k) v[k] = (short)f2bf(outv[g*8 + k]);
            *(short8*)&alds[t*64 + ((g ^ sw) * 8)] = v;
        }
    }
    __syncthreads();

    const int wid = t >> 6, ln = t & 63;
    const int l15 = ln & 15, q = ln >> 4;

    // ---- preload a-frags once (reused across all 36 n-tiles) ----
    short8 afrag[4][2];
#pragma unroll
    for (int mg = 0; mg < 4; ++mg) {
        const int px = (wid*4 + mg)*16 + l15;
        const int sw = px & 7;
#pragma unroll
        for (int ks = 0; ks < 2; ++ks)
            afrag[mg][ks] = *(const short8*)&alds[px*64 + (((ks*4 + q) ^ sw) * 8)];
    }

    f32x4 y_acc[4][4];   // [mg][ntoc]; lane: px-col=l15, oc = ntoc*16 + q*4 + reg
#pragma unroll
    for (int mg = 0; mg < 4; ++mg)
#pragma unroll
        for (int nt = 0; nt < 4; ++nt) y_acc[mg][nt] = (f32x4){0.f,0.f,0.f,0.f};

    // ---- phase 2: SWAPPED operands; j runtime loop bounds the live window ----
#pragma unroll 1
    for (int j = 0; j < 9; ++j) {
        const int dh = j / 3, dw = j - dh*3;
#pragma unroll
        for (int ntoc = 0; ntoc < 4; ++ntoc) {
            const short8 bf0 = *(const short8*)&wb3[((size_t)(j*64 + ntoc*16 + l15))*64 + q*8];
            const short8 bf1 = *(const short8*)&wb3[((size_t)(j*64 + ntoc*16 + l15))*64 + 32 + q*8];
            const f32x4 b3v4 = *(const f32x4*)&b3r[j*64 + ntoc*16 + q*4];
#pragma unroll
            for (int mg = 0; mg < 4; ++mg) {
                f32x4 a = b3v4;
                a = __builtin_amdgcn_mfma_f32_16x16x32_bf16(bf0, afrag[mg][0], a, 0, 0, 0);
                a = __builtin_amdgcn_mfma_f32_16x16x32_bf16(bf1, afrag[mg][1], a, 0, 0, 0);
                const int rr = wid*4 + mg;
                const us4 pv = *(const us4*)
                    &tile[((rr+dh)*18 + l15 + dw)*TS + ntoc*16 + q*4];
#pragma unroll
                for (int reg = 0; reg < 4; ++reg)
                    y_acc[mg][ntoc][reg] = fmaf(a[reg], bf2f(pv[reg]), y_acc[mg][ntoc][reg]);
            }
        }
    }

    // ---- leaky + swizzled ybuf (reuse alds) + coalesced NHWC writeout ----
    __syncthreads();                          // all alds reads done
    unsigned short* ybuf = alds;
#pragma unroll
    for (int mg = 0; mg < 4; ++mg) {
        const int rr = wid*4 + mg;
        const int px = rr*16 + l15;
        const int swy = (px & 7) << 1;        // even XOR: keeps 16B pairs intact
#pragma unroll
        for (int ntoc = 0; ntoc < 4; ++ntoc) {
            us4 ov;
#pragma unroll
            for (int reg = 0; reg < 4; ++reg) {
                float v = y_acc[mg][ntoc][reg];
                v = (v >= 0.f) ? v : 0.2f * v;
                ov[reg] = f2bf(v);
            }
            const int slot = (ntoc*4 + q) ^ swy;
            *(us4*)&ybuf[px*64 + slot*4] = ov;
        }
    }
    __syncthreads();
    for (int id = t; id < 2048; id += 256) {
        int px = id >> 3, g = id & 7;
        const int swy = (px & 7) << 1;
        short8 v = *(const short8*)&ybuf[px*64 + ((2*g) ^ swy)*4];
        int rr = px >> 4, cw = px & 15;
        *(short8*)&y[((size_t)(b*HW) + (h0+rr)*WW + (wc0+cw))*C + g*8] = v;
    }
}

// ---------------------------------------------------------------------------
// Cooperative mega-kernel: prep -> conv0+mean -> fused -> convf with 3 grid
// syncs. Grid 512 = exactly 2 blocks/CU (LDS 79.7 KB, VGPR capped 256 via
// __launch_bounds__(256,2)) -> all blocks co-resident, coop launch valid.
// Replaces 4 dispatches (+~70 us of launch/gap overhead) with 1.
// ---------------------------------------------------------------------------
__global__ __launch_bounds__(256, 2) void mega_kernel(
    const float* __restrict__ x,
    const float* __restrict__ w0, const float* __restrict__ b0,
    const float* __restrict__ w1, const float* __restrict__ b1,
    const float* __restrict__ w2, const float* __restrict__ b2,
    const float* __restrict__ w3, const float* __restrict__ b3,
    const float* __restrict__ wf, const float* __restrict__ bf,
    float* __restrict__ out,
    unsigned short* __restrict__ x0, unsigned short* __restrict__ y,
    float* __restrict__ m,
    unsigned short* __restrict__ wb0, unsigned short* __restrict__ wbf,
    unsigned short* __restrict__ wb3, float* __restrict__ b3r)
{
    __shared__ __align__(16) unsigned short tile[NPX*TS];   // 46656 B
    __shared__ __align__(16) unsigned short alds[256*64];   // 32768 B (A/ybuf/sred)
    __shared__ __align__(16) float att[64];                 // 256 B

    cg::grid_group grid = cg::this_grid();

    const int b   = blockIdx.z;
    const int h0  = blockIdx.y * 16;
    const int wc0 = blockIdx.x * 16;
    const int t   = threadIdx.x;
    const int bid = (blockIdx.z * 8 + blockIdx.y) * 8 + blockIdx.x;
    const int gt  = bid * 256 + t;            // 0 .. 131071

    // ---- phase P: weight prep, distributed over the whole grid ----
    if (gt < C*C*9) {                         // 36864 items, single pass
        int p = gt % 9; int rest = gt / 9; int ci = rest % C; int oc = rest / C;
        wb0[(p*C + oc)*C + ci] = f2bf(w0[gt]);
        wbf[(p*C + oc)*C + ci] = f2bf(wf[gt]);
        int j = gt >> 12, oc2 = (gt >> 6) & 63, k = gt & 63;
        wb3[gt] = f2bf(w3[(oc2*9 + j)*C + k]);   // dst ((j*64+oc)*64+k)
    }
    if (gt < 9*C) { int j = gt >> 6, oc = gt & 63; b3r[gt] = b3[oc*9 + j]; }
    if (gt < BB*C) m[gt] = 0.f;
    grid.sync();

    // ---- phase A: conv0 (+bias) -> x0 bf16 NHWC, fused spatial mean -> m ----
    conv_phase<true>(x, wb0, b0, nullptr, x0, m, tile, (float*)alds, b, h0, wc0, t);
    grid.sync();

    // ---- phase B: depthwise+ECA+dynamic-filter conv+leaky -> y bf16 NHWC ----
    fused_phase(x0, w1, b1, w2, b2, wb3, b3r, m, y, tile, alds, att, b, h0, wc0, t);
    grid.sync();

    // ---- phase C: convf (+bias+residual x) -> out fp32 NCHW ----
    conv_phase<false>(y, wbf, bf, x, out, nullptr, tile, (float*)alds, b, h0, wc0, t);
}

// ---------------------------------------------------------------------------
// Fallback path (proven round-6 4-dispatch pipeline) in case cooperative
// launch is rejected (e.g. by graph capture). Same phase bodies.
// ---------------------------------------------------------------------------
__global__ __launch_bounds__(256) void prep_kernel(
    const float* __restrict__ w0, const float* __restrict__ wf,
    const float* __restrict__ w3, const float* __restrict__ b3,
    unsigned short* __restrict__ wb0, unsigned short* __restrict__ wbf,
    unsigned short* __restrict__ wb3, float* __restrict__ b3r,
    float* __restrict__ m)
{
    const int t = blockIdx.x * 256 + threadIdx.x;
    for (int i = t; i < C*C*9; i += 32*256) {
        int p = i % 9; int rest = i / 9; int ci = rest % C; int oc = rest / C;
        wb0[(p*C + oc)*C + ci] = f2bf(w0[i]);
        wbf[(p*C + oc)*C + ci] = f2bf(wf[i]);
    }
    for (int i = t; i < 9*C*C; i += 32*256) {
        int j = i >> 12, oc = (i >> 6) & 63, k = i & 63;
        wb3[i] = f2bf(w3[(oc*9 + j)*C + k]);
    }
    for (int i = t; i < 9*C; i += 32*256) {
        int j = i >> 6, oc = i & 63;
        b3r[i] = b3[oc*9 + j];
    }
    for (int i = t; i < BB*C; i += 32*256) m[i] = 0.f;
}

template<bool FIRST>
__global__ __launch_bounds__(256) void conv_mfma_kernel(
    const void* __restrict__ in,
    const unsigned short* __restrict__ wb,
    const float* __restrict__ bias,
    const float* __restrict__ res,
    void* __restrict__ outp,
    float* __restrict__ m)
{
    __shared__ __align__(16) unsigned short tile[NPX*TS];
    __shared__ __align__(16) float sred[4*4*16];
    conv_phase<FIRST>(in, wb, bias, res, outp, m, tile, sred,
                      blockIdx.z, blockIdx.y*16, blockIdx.x*16, threadIdx.x);
}

__global__ __launch_bounds__(256) void fused_kernel(
    const unsigned short* __restrict__ x0,
    const float* __restrict__ w1, const float* __restrict__ b1,
    const float* __restrict__ w2, const float* __restrict__ b2,
    const unsigned short* __restrict__ wb3,
    const float* __restrict__ b3r,
    const float* __restrict__ m,
    unsigned short* __restrict__ y)
{
    __shared__ __align__(16) unsigned short tile[NPX*TS];
    __shared__ __align__(16) unsigned short alds[256*64];
    __shared__ __align__(16) float att[64];
    fused_phase(x0, w1, b1, w2, b2, wb3, b3r, m, y, tile, alds, att,
                blockIdx.z, blockIdx.y*16, blockIdx.x*16, threadIdx.x);
}

extern "C" void kernel_launch(void* const* d_in, const int* in_sizes, int n_in,
                              void* d_out, int out_size, void* d_ws, size_t ws_size,
                              hipStream_t stream) {
    const float* x  = (const float*)d_in[0];
    const float* w0 = (const float*)d_in[1];
    const float* b0 = (const float*)d_in[2];
    const float* w1 = (const float*)d_in[3];
    const float* b1 = (const float*)d_in[4];
    const float* w2 = (const float*)d_in[5];
    const float* b2 = (const float*)d_in[6];
    const float* w3 = (const float*)d_in[7];
    const float* b3 = (const float*)d_in[8];
    const float* wf = (const float*)d_in[9];
    const float* bf = (const float*)d_in[10];
    float* out = (float*)d_out;

    unsigned short* x0  = (unsigned short*)d_ws;            // [B,H,W,C] bf16
    unsigned short* y   = x0 + (size_t)BB*HW*C;             // [B,H,W,C] bf16
    float*          m   = (float*)(y + (size_t)BB*HW*C);    // [B*C]
    unsigned short* wb0 = (unsigned short*)(m + BB*C);      // [9][64][64] bf16
    unsigned short* wbf = wb0 + 9*C*C;
    unsigned short* wb3 = wbf + 9*C*C;                      // [9][64][64] bf16
    float*          b3r = (float*)(wb3 + 9*C*C);            // [9][64]

    void* args[] = {
        (void*)&x,  (void*)&w0, (void*)&b0, (void*)&w1, (void*)&b1,
        (void*)&w2, (void*)&b2, (void*)&w3, (void*)&b3, (void*)&wf,
        (void*)&bf, (void*)&out, (void*)&x0, (void*)&y,  (void*)&m,
        (void*)&wb0, (void*)&wbf, (void*)&wb3, (void*)&b3r
    };
    hipError_t e = hipLaunchCooperativeKernel(
        mega_kernel, dim3(8,8,8), dim3(256,1,1), args, 0u, stream);

    if (e != hipSuccess) {
        // fallback: proven 4-dispatch pipeline (round-6 behavior, ~210 us)
        prep_kernel<<<32, 256, 0, stream>>>(w0, wf, w3, b3, wb0, wbf, wb3, b3r, m);
        conv_mfma_kernel<true><<<dim3(8,8,8), 256, 0, stream>>>(x, wb0, b0, nullptr, x0, m);
        fused_kernel<<<dim3(8,8,8), 256, 0, stream>>>(x0, w1, b1, w2, b2, wb3, b3r, m, y);
        conv_mfma_kernel<false><<<dim3(8,8,8), 256, 0, stream>>>(y, wbf, bf, x, out, nullptr);
    }
}

// Round 8
// 207.398 us; speedup vs baseline: 1.7980x; 1.7980x over previous
//
#include <hip/hip_runtime.h>

#define BB 8
#define C 64
#define HH 128
#define WW 128
#define HW (HH*WW)

#define TS 72        // LDS channel stride (ushorts) for halo tile
#define NPX 324      // 18*18 halo tile pixels

typedef __attribute__((ext_vector_type(8))) short short8;
typedef __attribute__((ext_vector_type(4))) unsigned short us4;
typedef __attribute__((ext_vector_type(4))) float f32x4;

__device__ inline unsigned short f2bf(float f) {
    union { float f; unsigned u; } v; v.f = f;
    unsigned r = v.u + 0x7fff + ((v.u >> 16) & 1);   // RNE
    return (unsigned short)(r >> 16);
}
__device__ inline float bf2f(unsigned short h) {
    union { unsigned u; float f; } v; v.u = ((unsigned)h) << 16;
    return v.f;
}

// ---------------------------------------------------------------------------
// Prep: wb[p][oc][ci] (B^T bf16) for conv0/convf; wb3[j][oc][k] bf16 and
// b3r[j][oc] for the dynamic-filter GEMM; zero m.
// ---------------------------------------------------------------------------
__global__ __launch_bounds__(256) void prep_kernel(
    const float* __restrict__ w0, const float* __restrict__ wf,
    const float* __restrict__ w3, const float* __restrict__ b3,
    unsigned short* __restrict__ wb0, unsigned short* __restrict__ wbf,
    unsigned short* __restrict__ wb3, float* __restrict__ b3r,
    float* __restrict__ m)
{
    const int t = blockIdx.x * 256 + threadIdx.x;
    for (int i = t; i < C*C*9; i += 32*256) {
        int p = i % 9; int rest = i / 9; int ci = rest % C; int oc = rest / C;
        wb0[(p*C + oc)*C + ci] = f2bf(w0[i]);
        wbf[(p*C + oc)*C + ci] = f2bf(wf[i]);
    }
    for (int i = t; i < 9*C*C; i += 32*256) {        // dst index: ((j*64+oc)*64+k)
        int j = i >> 12, oc = (i >> 6) & 63, k = i & 63;
        wb3[i] = f2bf(w3[(oc*9 + j)*C + k]);
    }
    for (int i = t; i < 9*C; i += 32*256) {          // b3r[j*64+oc] = b3[oc*9+j]
        int j = i >> 6, oc = i & 63;
        b3r[i] = b3[oc*9 + j];
    }
    for (int i = t; i < BB*C; i += 32*256) m[i] = 0.f;
}

// ---------------------------------------------------------------------------
// MFMA implicit-GEMM 3x3 conv. 16x16 px tile, 256 threads (4 waves), all 64
// oc per wave. FULL p-loop unroll + no min-waves bound (~248 VGPR, 2 blk/CU):
// round-4 evidence shows this beats the (256,3)+unroll1 variant by ~34 us
// total (hoisted weight prefetch vs per-tap latency exposure).
// FIRST:  in = x fp32 NCHW -> out = x0 bf16 NHWC (+bias) + fused mean -> m
// !FIRST: in = y bf16 NHWC -> out = fp32 NCHW (+bias+residual x)
// ---------------------------------------------------------------------------
template<bool FIRST>
__global__ __launch_bounds__(256) void conv_mfma_kernel(
    const void* __restrict__ in,
    const unsigned short* __restrict__ wb,   // [9][64][64] bf16 (B^T)
    const float* __restrict__ bias,
    const float* __restrict__ res,
    void* __restrict__ outp,
    float* __restrict__ m)
{
    __shared__ __align__(16) unsigned short tile[NPX*TS];  // 46.7 KB
    __shared__ __align__(16) float sred[4][4][16];         // 1 KB (mean reduce)
    const int b  = blockIdx.z;
    const int h0 = blockIdx.y * 16;
    const int w0 = blockIdx.x * 16;
    const int t  = threadIdx.x;

    {
        const int pxi = t & 31, g = t >> 5;          // g = channel octet
        for (int px = pxi; px < NPX; px += 32) {
            int th = px / 18, tw = px - th*18;
            int gh = h0 + th - 1, gw = w0 + tw - 1;
            short8 v = {0,0,0,0,0,0,0,0};
            if ((unsigned)gh < HH && (unsigned)gw < WW) {
                if (FIRST) {
                    const float* sp = (const float*)in
                        + ((size_t)(b*C + g*8)*HW + gh*WW + gw);
#pragma unroll
                    for (int k = 0; k < 8; ++k) v[k] = (short)f2bf(sp[k*HW]);
                } else {
                    v = *(const short8*)((const unsigned short*)in
                        + ((size_t)(b*HW) + gh*WW + gw)*C + g*8);
                }
            }
            *(short8*)&tile[px*TS + g*8] = v;
        }
    }
    __syncthreads();

    const int wid = t >> 6, ln = t & 63;
    const int l15 = ln & 15, q = ln >> 4;

    f32x4 acc[4][4];
#pragma unroll
    for (int mg = 0; mg < 4; ++mg)
#pragma unroll
        for (int nt = 0; nt < 4; ++nt) acc[mg][nt] = (f32x4){0.f,0.f,0.f,0.f};

#pragma unroll
    for (int p = 0; p < 9; ++p) {
        const int dh = p / 3, dw = p % 3;
#pragma unroll
        for (int ks = 0; ks < 2; ++ks) {
            short8 bfrag[4];
#pragma unroll
            for (int nt = 0; nt < 4; ++nt)
                bfrag[nt] = *(const short8*)&wb[((size_t)(p*C) + nt*16 + l15)*C + ks*32 + q*8];
            short8 afrag[4];
#pragma unroll
            for (int mg = 0; mg < 4; ++mg) {
                const int r = wid*4 + mg;
                afrag[mg] = *(const short8*)&tile[((r+dh)*18 + l15 + dw)*TS + ks*32 + q*8];
            }
#pragma unroll
            for (int mg = 0; mg < 4; ++mg)
#pragma unroll
                for (int nt = 0; nt < 4; ++nt)
                    acc[mg][nt] = __builtin_amdgcn_mfma_f32_16x16x32_bf16(
                        afrag[mg], bfrag[nt], acc[mg][nt], 0, 0, 0);
        }
    }

    if (FIRST) {
        unsigned short* x0o = (unsigned short*)outp;
#pragma unroll
        for (int nt = 0; nt < 4; ++nt) {
            const int oc = nt*16 + l15;
            const float bv = bias[oc];
            float s = 0.f;
#pragma unroll
            for (int mg = 0; mg < 4; ++mg) {
                const int hh = h0 + wid*4 + mg;
#pragma unroll
                for (int reg = 0; reg < 4; ++reg) {
                    const int wwp = w0 + q*4 + reg;
                    const unsigned short sv = f2bf(acc[mg][nt][reg] + bv);
                    x0o[((size_t)(b*HW) + hh*WW + wwp)*C + oc] = sv;
                    s += bf2f(sv);   // mean of rounded bf16 values (matches old path)
                }
            }
            s += __shfl_xor(s, 16);  // sum over q (px-col groups)
            s += __shfl_xor(s, 32);
            if (q == 0) sred[wid][nt][l15] = s;
        }
        __syncthreads();
        if (t < 64) {
            float s = sred[0][t >> 4][t & 15] + sred[1][t >> 4][t & 15]
                    + sred[2][t >> 4][t & 15] + sred[3][t >> 4][t & 15];
            atomicAdd(&m[b*C + t], s * (1.f/(float)HW));
        }
    } else {
        float* outg = (float*)outp;
#pragma unroll
        for (int mg = 0; mg < 4; ++mg) {
            const int hh = h0 + wid*4 + mg;
#pragma unroll
            for (int nt = 0; nt < 4; ++nt) {
                const int oc = nt*16 + l15;
                const float bv = bias[oc];
                const size_t base = (size_t)(b*C + oc)*HW + hh*WW + w0 + q*4;
                const float4 rv = *(const float4*)&res[base];
                float4 ov;
                ov.x = acc[mg][nt][0] + bv + rv.x;
                ov.y = acc[mg][nt][1] + bv + rv.y;
                ov.z = acc[mg][nt][2] + bv + rv.z;
                ov.w = acc[mg][nt][3] + bv + rv.w;
                *(float4*)&outg[base] = ov;
            }
        }
    }
}

// ---------------------------------------------------------------------------
// Fused (round-6 proven, 88 VGPR / 45 us): depthwise3x3 + ECA (att[64]) ->
// LDS A-matrix (XOR-swizzled); SWAPPED-operand MFMA filter GEMM (reg-axis
// walks oc -> us4 vector consume from resident tile); j-loop unroll-capped
// to keep hoisted loads inside the register budget (full unroll = 28 MB
// spill, round 4); leaky; swizzled ybuf -> coalesced NHWC bf16 store.
// ---------------------------------------------------------------------------
__global__ __launch_bounds__(256) void fused_kernel(
    const unsigned short* __restrict__ x0,
    const float* __restrict__ w1, const float* __restrict__ b1,
    const float* __restrict__ w2, const float* __restrict__ b2,
    const unsigned short* __restrict__ wb3,  // [9][64][64] bf16 (B^T, n'=j*64+oc)
    const float* __restrict__ b3r,           // [9][64]
    const float* __restrict__ m,
    unsigned short* __restrict__ y)
{
    __shared__ __align__(16) unsigned short tile[NPX*TS];   // 46656 B
    __shared__ __align__(16) unsigned short alds[256*64];   // 32768 B; reused as ybuf
    __shared__ __align__(16) float att[64];                 // 256 B
    const int b  = blockIdx.z;
    const int h0 = blockIdx.y * 16;
    const int w0 = blockIdx.x * 16;
    const int t  = threadIdx.x;

    if (t < 64) {   // per-block ECA + b1 term (uniform over pixels)
        const float mc = m[b*C + t];
        const float mp = (t > 0)  ? m[b*C + t - 1] : 0.f;
        const float mn = (t < 63) ? m[b*C + t + 1] : 0.f;
        att[t] = b1[t] + fmaf(w2[0], mp, fmaf(w2[1], mc, fmaf(w2[2], mn, b2[0])));
    }
    {
        const int pxi = t & 31, g = t >> 5;
        for (int px = pxi; px < NPX; px += 32) {
            int th = px / 18, tw = px - th*18;
            int gh = h0 + th - 1, gw = w0 + tw - 1;
            short8 v = {0,0,0,0,0,0,0,0};
            if ((unsigned)gh < HH && (unsigned)gw < WW)
                v = *(const short8*)&x0[((size_t)(b*HW) + gh*WW + gw)*C + g*8];
            *(short8*)&tile[px*TS + g*8] = v;
        }
    }
    __syncthreads();

    const int r = t >> 4, cc = t & 15;
    const unsigned short* tbase = tile + (r*18 + cc)*TS;

    // ---- phase 1: depthwise + att -> outv[64] ----
    float outv[64];
#pragma unroll
    for (int g = 0; g < 8; ++g) {
        float dw8[8];
#pragma unroll
        for (int k = 0; k < 8; ++k) dw8[k] = 0.f;
#pragma unroll
        for (int j = 0; j < 9; ++j) {
            short8 v = *(const short8*)&tbase[((j/3)*18 + (j%3))*TS + g*8];
#pragma unroll
            for (int k = 0; k < 8; ++k)
                dw8[k] = fmaf(w1[(g*8+k)*9 + j], bf2f((unsigned short)v[k]), dw8[k]);
        }
#pragma unroll
        for (int k = 0; k < 8; ++k) {
            const int c = g*8 + k;
            outv[c] = dw8[k] + att[c];
        }
    }

    // ---- write A[px][k] bf16 to LDS, XOR-swizzled 16B groups ----
    {
        const int sw = t & 7;
#pragma unroll
        for (int g = 0; g < 8; ++g) {
            short8 v;
#pragma unroll
            for (int k = 0; k < 8; ++k) v[k] = (short)f2bf(outv[g*8 + k]);
            *(short8*)&alds[t*64 + ((g ^ sw) * 8)] = v;
        }
    }
    __syncthreads();

    const int wid = t >> 6, ln = t & 63;
    const int l15 = ln & 15, q = ln >> 4;

    // ---- preload a-frags once (reused across all 36 n-tiles) ----
    short8 afrag[4][2];
#pragma unroll
    for (int mg = 0; mg < 4; ++mg) {
        const int px = (wid*4 + mg)*16 + l15;
        const int sw = px & 7;
#pragma unroll
        for (int ks = 0; ks < 2; ++ks)
            afrag[mg][ks] = *(const short8*)&alds[px*64 + (((ks*4 + q) ^ sw) * 8)];
    }

    f32x4 y_acc[4][4];   // [mg][ntoc]; lane: px-col=l15, oc = ntoc*16 + q*4 + reg
#pragma unroll
    for (int mg = 0; mg < 4; ++mg)
#pragma unroll
        for (int nt = 0; nt < 4; ++nt) y_acc[mg][nt] = (f32x4){0.f,0.f,0.f,0.f};

    // ---- phase 2: SWAPPED operands; j runtime loop bounds the live window ----
#pragma unroll 1
    for (int j = 0; j < 9; ++j) {
        const int dh = j / 3, dw = j - dh*3;
#pragma unroll
        for (int ntoc = 0; ntoc < 4; ++ntoc) {
            const short8 bf0 = *(const short8*)&wb3[((size_t)(j*64 + ntoc*16 + l15))*64 + q*8];
            const short8 bf1 = *(const short8*)&wb3[((size_t)(j*64 + ntoc*16 + l15))*64 + 32 + q*8];
            const f32x4 b3v4 = *(const f32x4*)&b3r[j*64 + ntoc*16 + q*4];
#pragma unroll
            for (int mg = 0; mg < 4; ++mg) {
                f32x4 a = b3v4;
                a = __builtin_amdgcn_mfma_f32_16x16x32_bf16(bf0, afrag[mg][0], a, 0, 0, 0);
                a = __builtin_amdgcn_mfma_f32_16x16x32_bf16(bf1, afrag[mg][1], a, 0, 0, 0);
                const int rr = wid*4 + mg;
                const us4 pv = *(const us4*)
                    &tile[((rr+dh)*18 + l15 + dw)*TS + ntoc*16 + q*4];
#pragma unroll
                for (int reg = 0; reg < 4; ++reg)
                    y_acc[mg][ntoc][reg] = fmaf(a[reg], bf2f(pv[reg]), y_acc[mg][ntoc][reg]);
            }
        }
    }

    // ---- leaky + swizzled ybuf (reuse alds) + coalesced NHWC writeout ----
    __syncthreads();                          // all alds reads done
    unsigned short* ybuf = alds;
#pragma unroll
    for (int mg = 0; mg < 4; ++mg) {
        const int rr = wid*4 + mg;
        const int px = rr*16 + l15;
        const int swy = (px & 7) << 1;        // even XOR: keeps 16B pairs intact
#pragma unroll
        for (int ntoc = 0; ntoc < 4; ++ntoc) {
            us4 ov;
#pragma unroll
            for (int reg = 0; reg < 4; ++reg) {
                float v = y_acc[mg][ntoc][reg];
                v = (v >= 0.f) ? v : 0.2f * v;
                ov[reg] = f2bf(v);
            }
            const int slot = (ntoc*4 + q) ^ swy;
            *(us4*)&ybuf[px*64 + slot*4] = ov;
        }
    }
    __syncthreads();
    for (int id = t; id < 2048; id += 256) {
        int px = id >> 3, g = id & 7;
        const int swy = (px & 7) << 1;
        short8 v = *(const short8*)&ybuf[px*64 + ((2*g) ^ swy)*4];
        int rr = px >> 4, cw = px & 15;
        *(short8*)&y[((size_t)(b*HW) + (h0+rr)*WW + (w0+cw))*C + g*8] = v;
    }
}

extern "C" void kernel_launch(void* const* d_in, const int* in_sizes, int n_in,
                              void* d_out, int out_size, void* d_ws, size_t ws_size,
                              hipStream_t stream) {
    const float* x  = (const float*)d_in[0];
    const float* w0 = (const float*)d_in[1];
    const float* b0 = (const float*)d_in[2];
    const float* w1 = (const float*)d_in[3];
    const float* b1 = (const float*)d_in[4];
    const float* w2 = (const float*)d_in[5];
    const float* b2 = (const float*)d_in[6];
    const float* w3 = (const float*)d_in[7];
    const float* b3 = (const float*)d_in[8];
    const float* wf = (const float*)d_in[9];
    const float* bf = (const float*)d_in[10];
    float* out = (float*)d_out;

    unsigned short* x0  = (unsigned short*)d_ws;            // [B,H,W,C] bf16
    unsigned short* y   = x0 + (size_t)BB*HW*C;             // [B,H,W,C] bf16
    float*          m   = (float*)(y + (size_t)BB*HW*C);    // [B*C]
    unsigned short* wb0 = (unsigned short*)(m + BB*C);      // [9][64][64] bf16
    unsigned short* wbf = wb0 + 9*C*C;
    unsigned short* wb3 = wbf + 9*C*C;                      // [9][64][64] bf16
    float*          b3r = (float*)(wb3 + 9*C*C);            // [9][64]

    prep_kernel<<<32, 256, 0, stream>>>(w0, wf, w3, b3, wb0, wbf, wb3, b3r, m);
    conv_mfma_kernel<true><<<dim3(8,8,8), 256, 0, stream>>>(x, wb0, b0, nullptr, x0, m);
    fused_kernel<<<dim3(8,8,8), 256, 0, stream>>>(x0, w1, b1, w2, b2, wb3, b3r, m, y);
    conv_mfma_kernel<false><<<dim3(8,8,8), 256, 0, stream>>>(y, wbf, bf, x, out, nullptr);
}